// Round 1
// baseline (243.415 us; speedup 1.0000x reference)
//
#include <hip/hip_runtime.h>
#include <math.h>

#define BN 1024
#define NV 5023
#define NF 9976
#define NL 68
#define KBET 150
#define KTOT 192
#define OSTR 15273   // (V+L)*3

// ---------------- workspace layout (floats) ----------------
// O_JSX  = 0       : Jsx[15][152]            (2280, reserve 4096)
// O_PART = 4096    : partials[79][2400]      (189600, reserve 196608)
// O_ET   = 200704  : E_T[192][1024]          (196608)
// O_AREL = 397312  : A_rel[1024][60]         (61440)

// ============ K1a: partial reduce  Js[j][c][l] = sum_v Jreg[j,v]*SDext[v,c,l] ============
#define VPI 8
__global__ __launch_bounds__(256) void k1a(const float* __restrict__ sd,
                                           const float* __restrict__ vt,
                                           const float* __restrict__ jreg,
                                           float* __restrict__ part) {
  __shared__ float row8[VPI * 456];
  __shared__ float jr8[VPI * 8];
  int t = threadIdx.x;
  int vbase0 = blockIdx.x * 64;
  float acc[10];
#pragma unroll
  for (int m = 0; m < 10; ++m) acc[m] = 0.f;
  int jc = t / 16, li = t % 16;
  int j = jc / 3, c = jc % 3;
  for (int it = 0; it < 8; ++it) {
    int vb = vbase0 + it * VPI;
    __syncthreads();
    for (int idx = t; idx < VPI * 458; idx += 256) {
      int vv = idx / 458, r = idx % 458;
      int v = vb + vv;
      if (r < 453) {
        int cc = r / 151, l = r % 151;
        float val = 0.f;
        if (v < NV) val = (l < 150) ? sd[v * 450 + cc * 150 + l] : vt[v * 3 + cc];
        row8[vv * 456 + cc * 151 + l] = val;
      } else {
        float val = 0.f;
        if (v < NV) val = jreg[(r - 453) * NV + v];
        jr8[vv * 8 + (r - 453)] = val;
      }
    }
    __syncthreads();
    if (t < 240) {
#pragma unroll
      for (int vv = 0; vv < VPI; ++vv) {
        float wv = jr8[vv * 8 + j];
#pragma unroll
        for (int m = 0; m < 10; ++m) {
          int l = li + 16 * m;
          if (l < 151) acc[m] += wv * row8[vv * 456 + c * 151 + l];
        }
      }
    }
  }
  if (t < 240) {
#pragma unroll
    for (int m = 0; m < 10; ++m) {
      int l = li + 16 * m;
      if (l < 151) part[blockIdx.x * 2400 + jc * 160 + l] = acc[m];
    }
  }
}

// ============ K1b: reduce 79 partials -> Jsx[15][152] (col 150 = Jt) ============
__global__ void k1b(const float* __restrict__ part, float* __restrict__ jsx) {
  int jc = blockIdx.x;
  int t = threadIdx.x;
  if (t < 151) {
    float s = 0.f;
    for (int ch = 0; ch < 79; ++ch) s += part[ch * 2400 + jc * 160 + t];
    jsx[jc * 152 + t] = s;
  }
}

// ============ K2: per-batch J, Rodrigues, chain, A_rel, E_T ============
__global__ __launch_bounds__(64) void k2(const float* __restrict__ shp,
                                         const float* __restrict__ expr,
                                         const float* __restrict__ pose,
                                         const float* __restrict__ eye,
                                         const float* __restrict__ jsx,
                                         float* __restrict__ et,
                                         float* __restrict__ arel) {
  int b = blockIdx.x, t = threadIdx.x;
  __shared__ float bet[150];
  __shared__ float Rm[5][9];
  __shared__ float Tl[5][16];
  __shared__ float Am[5][16];
  __shared__ float Jl[15];
  for (int i = t; i < 150; i += 64)
    bet[i] = (i < 100) ? shp[b * 100 + i] : expr[b * 50 + (i - 100)];
  __syncthreads();
  if (t < 60) {
    int jc = t >> 2, sub = t & 3;
    float acc = 0.f;
    for (int m = 0; m < 38; ++m) {
      int l = sub + 4 * m;
      if (l < 150) acc += jsx[jc * 152 + l] * bet[l];
      else if (l == 150) acc += jsx[jc * 152 + 150];
    }
    acc += __shfl_xor(acc, 1);
    acc += __shfl_xor(acc, 2);
    if (sub == 0) Jl[jc] = acc;
  }
  __syncthreads();
  if (t < 5) {
    float r0, r1, r2;
    if (t == 0)      { r0 = pose[b*6+0]; r1 = pose[b*6+1]; r2 = pose[b*6+2]; }
    else if (t == 2) { r0 = pose[b*6+3]; r1 = pose[b*6+4]; r2 = pose[b*6+5]; }
    else if (t == 3) { r0 = eye[b*6+0];  r1 = eye[b*6+1];  r2 = eye[b*6+2];  }
    else if (t == 4) { r0 = eye[b*6+3];  r1 = eye[b*6+4];  r2 = eye[b*6+5];  }
    else             { r0 = 0.f; r1 = 0.f; r2 = 0.f; }
    float ang = sqrtf(r0*r0 + r1*r1 + r2*r2 + 1e-16f);
    float ax = r0/ang, ay = r1/ang, az = r2/ang;
    float s = sinf(ang), cc = cosf(ang), o = 1.f - cc;
    float R0 = 1.f - o*(ay*ay+az*az);
    float R1 = -s*az + o*ax*ay;
    float R2 =  s*ay + o*ax*az;
    float R3 =  s*az + o*ax*ay;
    float R4 = 1.f - o*(ax*ax+az*az);
    float R5 = -s*ax + o*ay*az;
    float R6 = -s*ay + o*ax*az;
    float R7 =  s*ax + o*ay*az;
    float R8 = 1.f - o*(ax*ax+ay*ay);
    Rm[t][0]=R0; Rm[t][1]=R1; Rm[t][2]=R2; Rm[t][3]=R3; Rm[t][4]=R4;
    Rm[t][5]=R5; Rm[t][6]=R6; Rm[t][7]=R7; Rm[t][8]=R8;
    int par = (t == 0) ? -1 : ((t == 1) ? 0 : 1);
    float j0 = Jl[t*3+0], j1 = Jl[t*3+1], j2 = Jl[t*3+2];
    if (par >= 0) { j0 -= Jl[par*3+0]; j1 -= Jl[par*3+1]; j2 -= Jl[par*3+2]; }
    Tl[t][0]=R0; Tl[t][1]=R1; Tl[t][2]=R2;  Tl[t][3]=j0;
    Tl[t][4]=R3; Tl[t][5]=R4; Tl[t][6]=R5;  Tl[t][7]=j1;
    Tl[t][8]=R6; Tl[t][9]=R7; Tl[t][10]=R8; Tl[t][11]=j2;
    Tl[t][12]=0.f; Tl[t][13]=0.f; Tl[t][14]=0.f; Tl[t][15]=1.f;
  }
  __syncthreads();
  if (t < 16) Am[0][t] = Tl[0][t];
  __syncthreads();
  if (t < 16) {
    int m = t / 4, n = t % 4;
    float s = 0.f;
#pragma unroll
    for (int k = 0; k < 4; ++k) s += Am[0][m*4+k] * Tl[1][k*4+n];
    Am[1][t] = s;
  }
  __syncthreads();
  if (t < 48) {
    int jj = 2 + t / 16, tt = t % 16;
    int m = tt / 4, n = tt % 4;
    float s = 0.f;
#pragma unroll
    for (int k = 0; k < 4; ++k) s += Am[1][m*4+k] * Tl[jj][k*4+n];
    Am[jj][tt] = s;
  }
  __syncthreads();
  if (t < 60) {
    int j = t / 12, rr = (t % 12) / 4, cc = t % 4;
    float val = Am[j][rr*4+cc];
    if (cc == 3)
      val = Am[j][rr*4+3] - (Am[j][rr*4+0]*Jl[j*3+0] + Am[j][rr*4+1]*Jl[j*3+1] + Am[j][rr*4+2]*Jl[j*3+2]);
    arel[b * 60 + t] = val;
  }
  for (int k = t; k < 192; k += 64) {
    float val;
    if (k < 150) val = bet[k];
    else if (k < 186) {
      int kk = k - 150;
      int j = kk / 9 + 1, rc = kk % 9;
      val = Rm[j][rc] - ((rc == 0 || rc == 4 || rc == 8) ? 1.f : 0.f);
    } else if (k == 186) val = 1.f;
    else val = 0.f;
    et[k * 1024 + b] = val;
  }
}

// ============ K3: fused GEMM + LBS blend ============
__global__ __launch_bounds__(256) void k3(const float* __restrict__ sd,
                                          const float* __restrict__ pd,
                                          const float* __restrict__ vt,
                                          const float* __restrict__ et,
                                          const float* __restrict__ arel,
                                          const float* __restrict__ w,
                                          const float* __restrict__ tr,
                                          float* __restrict__ outp) {
  __shared__ __align__(16) float smem[32 * 132 + 32 * 196];
  float* Al = smem;            // [32][132]
  float* Bl = smem + 32 * 132; // [32][196]
  float* Ard = smem;           // epilogue: [128][64]
  float* wl = smem + 8192;     // [64][6]
  float* tl = smem + 8192 + 384; // [128][3]
  int tid = threadIdx.x;
  int tx = tid & 15, ty = tid >> 4;
  int v0 = blockIdx.x * 64;
  int b0 = blockIdx.y * 128;
  float acc[8][12];
#pragma unroll
  for (int i = 0; i < 8; ++i)
#pragma unroll
    for (int n = 0; n < 12; ++n) acc[i][n] = 0.f;

  for (int ks = 0; ks < 6; ++ks) {
    int k0 = ks * 32;
    {
      int tcol = tid & 31, trow = tid >> 5;
#pragma unroll
      for (int p = 0; p < 4; ++p) {
        int kk = trow + 8 * p;
        float4 va = *(const float4*)(et + (size_t)(k0 + kk) * 1024 + b0 + 4 * tcol);
        *(float4*)(Al + kk * 132 + 4 * tcol) = va;
      }
    }
    {
      int kl = tid & 31, rg = tid >> 5;
      int k = k0 + kl;
#pragma unroll
      for (int p = 0; p < 24; ++p) {
        int cv = rg + 8 * p;
        int c = cv >> 6, vv = cv & 63;
        int v = v0 + vv; if (v > NV - 1) v = NV - 1;
        float val;
        if (k < 150)       val = sd[(size_t)v * 450 + c * 150 + k];
        else if (k < 186)  val = pd[(size_t)(k - 150) * 15069 + v * 3 + c];
        else if (k == 186) val = vt[v * 3 + c];
        else               val = 0.f;
        Bl[kl * 196 + cv] = val;
      }
    }
    __syncthreads();
#pragma unroll 2
    for (int kk = 0; kk < 32; ++kk) {
      float a[8], bf[12];
      *(float4*)&a[0] = *(const float4*)(Al + kk * 132 + ty * 8);
      *(float4*)&a[4] = *(const float4*)(Al + kk * 132 + ty * 8 + 4);
      *(float4*)&bf[0] = *(const float4*)(Bl + kk * 196 + tx * 4);
      *(float4*)&bf[4] = *(const float4*)(Bl + kk * 196 + 64 + tx * 4);
      *(float4*)&bf[8] = *(const float4*)(Bl + kk * 196 + 128 + tx * 4);
#pragma unroll
      for (int i = 0; i < 8; ++i)
#pragma unroll
        for (int n = 0; n < 12; ++n)
          acc[i][n] = fmaf(a[i], bf[n], acc[i][n]);
    }
    __syncthreads();
  }
  // ---- epilogue staging ----
  for (int idx = tid; idx < 128 * 60; idx += 256) {
    int bb = idx / 60, r = idx % 60;
    Ard[bb * 64 + r] = arel[(size_t)(b0 + bb) * 60 + r];
  }
  for (int idx = tid; idx < 320; idx += 256) {
    int vv = idx / 5, j = idx % 5;
    int v = v0 + vv; if (v > NV - 1) v = NV - 1;
    wl[vv * 6 + j] = w[v * 5 + j];
  }
  for (int idx = tid; idx < 384; idx += 256) tl[idx] = tr[b0 * 3 + idx];
  __syncthreads();

#define STORE_V(T, vi_) do { \
    int v = v0 + tx * 4 + (vi_); \
    if (v < NV) { \
      float x = acc[i][(vi_)], y = acc[i][4 + (vi_)], z = acc[i][8 + (vi_)]; \
      float ox = fmaf(T[0], x, fmaf(T[1], y, fmaf(T[2], z, T[3] + t0))); \
      float oy = fmaf(T[4], x, fmaf(T[5], y, fmaf(T[6], z, T[7] + t1))); \
      float oz = fmaf(T[8], x, fmaf(T[9], y, fmaf(T[10], z, T[11] + t2))); \
      float* op = outp + (size_t)(b0 + b) * OSTR + (size_t)v * 3; \
      op[0] = ox; op[1] = oy; op[2] = oz; \
    } } while (0)

#pragma unroll
  for (int i = 0; i < 8; ++i) {
    int b = ty * 8 + i;
    float t0 = tl[b * 3 + 0], t1 = tl[b * 3 + 1], t2 = tl[b * 3 + 2];
#pragma unroll
    for (int h = 0; h < 2; ++h) {
      float T0[12], T1[12];
#pragma unroll
      for (int r = 0; r < 12; ++r) { T0[r] = 0.f; T1[r] = 0.f; }
      int vv0 = tx * 4 + 2 * h;
#pragma unroll
      for (int j = 0; j < 5; ++j) {
        float Aj[12];
        *(float4*)&Aj[0] = *(const float4*)(Ard + b * 64 + j * 12 + 0);
        *(float4*)&Aj[4] = *(const float4*)(Ard + b * 64 + j * 12 + 4);
        *(float4*)&Aj[8] = *(const float4*)(Ard + b * 64 + j * 12 + 8);
        float w0 = wl[vv0 * 6 + j], w1 = wl[(vv0 + 1) * 6 + j];
#pragma unroll
        for (int r = 0; r < 12; ++r) {
          T0[r] = fmaf(w0, Aj[r], T0[r]);
          T1[r] = fmaf(w1, Aj[r], T1[r]);
        }
      }
      STORE_V(T0, 2 * h);
      STORE_V(T1, 2 * h + 1);
    }
  }
#undef STORE_V
}

// ============ K4: landmarks ============
__global__ void k4(const int* __restrict__ faces, const int* __restrict__ lfi,
                   const float* __restrict__ bary, float* __restrict__ outp) {
  int idx = blockIdx.x * 256 + threadIdx.x;
  if (idx >= BN * NL * 3) return;
  int b = idx / (NL * 3), rem = idx % (NL * 3);
  int l = rem / 3, i = rem % 3;
  int fi = lfi[l];
  float s = 0.f;
#pragma unroll
  for (int f = 0; f < 3; ++f) {
    int vid = faces[fi * 3 + f];
    s += bary[l * 3 + f] * outp[(size_t)b * OSTR + (size_t)vid * 3 + i];
  }
  outp[(size_t)b * OSTR + (size_t)(NV + l) * 3 + i] = s;
}

extern "C" void kernel_launch(void* const* d_in, const int* in_sizes, int n_in,
                              void* d_out, int out_size, void* d_ws, size_t ws_size,
                              hipStream_t stream) {
  const float* shp  = (const float*)d_in[0];
  const float* expr = (const float*)d_in[1];
  const float* pose = (const float*)d_in[2];
  const float* eye  = (const float*)d_in[3];
  const float* tr   = (const float*)d_in[4];
  const float* vt   = (const float*)d_in[5];
  const float* sd   = (const float*)d_in[6];
  const float* pd   = (const float*)d_in[7];
  const float* jreg = (const float*)d_in[8];
  const float* w    = (const float*)d_in[9];
  const int* faces  = (const int*)d_in[10];
  const int* lfi    = (const int*)d_in[11];
  const float* bary = (const float*)d_in[12];
  float* ws = (float*)d_ws;
  float* jsx  = ws + 0;
  float* part = ws + 4096;
  float* et   = ws + 200704;
  float* arel = ws + 397312;
  float* outp = (float*)d_out;

  k1a<<<79, 256, 0, stream>>>(sd, vt, jreg, part);
  k1b<<<15, 160, 0, stream>>>(part, jsx);
  k2<<<1024, 64, 0, stream>>>(shp, expr, pose, eye, jsx, et, arel);
  k3<<<dim3(79, 8), 256, 0, stream>>>(sd, pd, vt, et, arel, w, tr, outp);
  k4<<<816, 256, 0, stream>>>(faces, lfi, bary, outp);
}

// Round 2
// 193.016 us; speedup vs baseline: 1.2611x; 1.2611x over previous
//
#include <hip/hip_runtime.h>
#include <math.h>

#define BN 1024
#define NV 5023
#define NL 68
#define NR 15069      // NV*3 rows of the basis
#define RS 15232      // padded row stride of Gt (>= 79*192, mult of 4)
#define OSTR 15273    // (V+L)*3
#define KTOT 192

// ---------------- workspace layout (floats) ----------------
#define O_JSX  0         // Jsx[15][152]
#define O_PART 4096      // part[79][2560]
#define O_ET   208896    // E_T[192][1024]
#define O_AREL 405504    // A_rel[1024][60]
#define O_GT   466944    // Gt[192][15232]  (~11.7 MB)

// ============ K0a: transpose shapedirs rows into Gt[k][r], r fastest ============
__global__ __launch_bounds__(256) void k0a(const float* __restrict__ sd,
                                           float* __restrict__ gt) {
  __shared__ float tile[32][33];
  int tx = threadIdx.x & 31, ty = threadIdx.x >> 5;
  int r0 = blockIdx.x * 32, k0 = blockIdx.y * 32;
#pragma unroll
  for (int q = 0; q < 4; ++q) {
    int r = r0 + ty + q * 8, k = k0 + tx;
    tile[ty + q * 8][tx] = (r < NR && k < 150) ? sd[(size_t)r * 150 + k] : 0.f;
  }
  __syncthreads();
#pragma unroll
  for (int q = 0; q < 4; ++q) {
    int k = k0 + ty + q * 8, r = r0 + tx;
    if (k < 150) gt[(size_t)k * RS + r] = tile[tx][ty + q * 8];
  }
}

// ============ K0b: Gt rows 150..191 = posedirs (already K-major) / vt / zeros ====
__global__ void k0b(const float* __restrict__ pd, const float* __restrict__ vt,
                    float* __restrict__ gt) {
  int idx = blockIdx.x * 256 + threadIdx.x;     // 42*RS total
  if (idx >= 42 * RS) return;
  int kk = 150 + idx / RS, r = idx % RS;
  float val = 0.f;
  if (r < NR) {
    if (kk < 186)       val = pd[(size_t)(kk - 150) * NR + r];
    else if (kk == 186) val = vt[r];
  }
  gt[(size_t)kk * RS + r] = val;
}

// ============ K1a: column-partials of Jreg * [shapedirs|vt] ============
__global__ __launch_bounds__(256) void k1a(const float* __restrict__ sd,
                                           const float* __restrict__ vt,
                                           const float* __restrict__ jreg,
                                           float* __restrict__ part) {
  int t = threadIdx.x, blk = blockIdx.x;
  int v0 = blk * 64;
  int c1 = t + 256;
  float a0[5], a1[5];
#pragma unroll
  for (int j = 0; j < 5; ++j) { a0[j] = 0.f; a1[j] = 0.f; }
#pragma unroll 4
  for (int i = 0; i < 64; ++i) {
    int v = v0 + i;
    if (v >= NV) break;
    float x0 = sd[(size_t)v * 450 + t];
    float x1 = (c1 < 450) ? sd[(size_t)v * 450 + c1]
             : (c1 < 453) ? vt[v * 3 + (c1 - 450)] : 0.f;
    float w0 = jreg[0 * NV + v], w1 = jreg[1 * NV + v], w2 = jreg[2 * NV + v];
    float w3 = jreg[3 * NV + v], w4 = jreg[4 * NV + v];
    a0[0] += w0 * x0; a1[0] += w0 * x1;
    a0[1] += w1 * x0; a1[1] += w1 * x1;
    a0[2] += w2 * x0; a1[2] += w2 * x1;
    a0[3] += w3 * x0; a1[3] += w3 * x1;
    a0[4] += w4 * x0; a1[4] += w4 * x1;
  }
  float* pp = part + (size_t)blk * 2560;
#pragma unroll
  for (int j = 0; j < 5; ++j) { pp[j * 512 + t] = a0[j]; pp[j * 512 + c1] = a1[j]; }
}

// ============ K1b: reduce partials -> Jsx[15][152] (col 150 = template part) =====
__global__ void k1b(const float* __restrict__ part, float* __restrict__ jsx) {
  int t = threadIdx.x;  // 512 threads
  for (int idx = t; idx < 5 * 453; idx += 512) {
    int j = idx / 453, col = idx % 453;
    float s = 0.f;
    for (int ch = 0; ch < 79; ++ch) s += part[(size_t)ch * 2560 + j * 512 + col];
    int c, l;
    if (col < 450) { c = col / 150; l = col % 150; } else { c = col - 450; l = 150; }
    jsx[(j * 3 + c) * 152 + l] = s;
  }
}

// ============ K2: per-batch J, Rodrigues, chain, A_rel, E_T ============
__global__ __launch_bounds__(64) void k2(const float* __restrict__ shp,
                                         const float* __restrict__ expr,
                                         const float* __restrict__ pose,
                                         const float* __restrict__ eye,
                                         const float* __restrict__ jsx,
                                         float* __restrict__ et,
                                         float* __restrict__ arel) {
  int b = blockIdx.x, t = threadIdx.x;
  __shared__ float bet[150];
  __shared__ float Rm[5][9];
  __shared__ float Tl[5][16];
  __shared__ float Am[5][16];
  __shared__ float Jl[15];
  for (int i = t; i < 150; i += 64)
    bet[i] = (i < 100) ? shp[b * 100 + i] : expr[b * 50 + (i - 100)];
  __syncthreads();
  if (t < 60) {
    int jc = t >> 2, sub = t & 3;
    float acc = 0.f;
    for (int m = 0; m < 38; ++m) {
      int l = sub + 4 * m;
      if (l < 150) acc += jsx[jc * 152 + l] * bet[l];
      else if (l == 150) acc += jsx[jc * 152 + 150];
    }
    acc += __shfl_xor(acc, 1);
    acc += __shfl_xor(acc, 2);
    if (sub == 0) Jl[jc] = acc;
  }
  __syncthreads();
  if (t < 5) {
    float r0, r1, r2;
    if (t == 0)      { r0 = pose[b*6+0]; r1 = pose[b*6+1]; r2 = pose[b*6+2]; }
    else if (t == 2) { r0 = pose[b*6+3]; r1 = pose[b*6+4]; r2 = pose[b*6+5]; }
    else if (t == 3) { r0 = eye[b*6+0];  r1 = eye[b*6+1];  r2 = eye[b*6+2];  }
    else if (t == 4) { r0 = eye[b*6+3];  r1 = eye[b*6+4];  r2 = eye[b*6+5];  }
    else             { r0 = 0.f; r1 = 0.f; r2 = 0.f; }
    float ang = sqrtf(r0*r0 + r1*r1 + r2*r2 + 1e-16f);
    float ax = r0/ang, ay = r1/ang, az = r2/ang;
    float s = sinf(ang), cc = cosf(ang), o = 1.f - cc;
    float R0 = 1.f - o*(ay*ay+az*az);
    float R1 = -s*az + o*ax*ay;
    float R2 =  s*ay + o*ax*az;
    float R3 =  s*az + o*ax*ay;
    float R4 = 1.f - o*(ax*ax+az*az);
    float R5 = -s*ax + o*ay*az;
    float R6 = -s*ay + o*ax*az;
    float R7 =  s*ax + o*ay*az;
    float R8 = 1.f - o*(ax*ax+ay*ay);
    Rm[t][0]=R0; Rm[t][1]=R1; Rm[t][2]=R2; Rm[t][3]=R3; Rm[t][4]=R4;
    Rm[t][5]=R5; Rm[t][6]=R6; Rm[t][7]=R7; Rm[t][8]=R8;
    int par = (t == 0) ? -1 : ((t == 1) ? 0 : 1);
    float j0 = Jl[t*3+0], j1 = Jl[t*3+1], j2 = Jl[t*3+2];
    if (par >= 0) { j0 -= Jl[par*3+0]; j1 -= Jl[par*3+1]; j2 -= Jl[par*3+2]; }
    Tl[t][0]=R0; Tl[t][1]=R1; Tl[t][2]=R2;  Tl[t][3]=j0;
    Tl[t][4]=R3; Tl[t][5]=R4; Tl[t][6]=R5;  Tl[t][7]=j1;
    Tl[t][8]=R6; Tl[t][9]=R7; Tl[t][10]=R8; Tl[t][11]=j2;
    Tl[t][12]=0.f; Tl[t][13]=0.f; Tl[t][14]=0.f; Tl[t][15]=1.f;
  }
  __syncthreads();
  if (t < 16) Am[0][t] = Tl[0][t];
  __syncthreads();
  if (t < 16) {
    int m = t / 4, n = t % 4;
    float s = 0.f;
#pragma unroll
    for (int k = 0; k < 4; ++k) s += Am[0][m*4+k] * Tl[1][k*4+n];
    Am[1][t] = s;
  }
  __syncthreads();
  if (t < 48) {
    int jj = 2 + t / 16, tt = t % 16;
    int m = tt / 4, n = tt % 4;
    float s = 0.f;
#pragma unroll
    for (int k = 0; k < 4; ++k) s += Am[1][m*4+k] * Tl[jj][k*4+n];
    Am[jj][tt] = s;
  }
  __syncthreads();
  if (t < 60) {
    int j = t / 12, rr = (t % 12) / 4, cc = t % 4;
    float val = Am[j][rr*4+cc];
    if (cc == 3)
      val = Am[j][rr*4+3] - (Am[j][rr*4+0]*Jl[j*3+0] + Am[j][rr*4+1]*Jl[j*3+1] + Am[j][rr*4+2]*Jl[j*3+2]);
    arel[b * 60 + t] = val;
  }
  for (int k = t; k < 192; k += 64) {
    float val;
    if (k < 150) val = bet[k];
    else if (k < 186) {
      int kk = k - 150;
      int j = kk / 9 + 1, rc = kk % 9;
      val = Rm[j][rc] - ((rc == 0 || rc == 4 || rc == 8) ? 1.f : 0.f);
    } else if (k == 186) val = 1.f;
    else val = 0.f;
    et[k * 1024 + b] = val;
  }
}

// ============ K3: fused GEMM (E_T x Gt) + LBS blend, 2-phase DMA pipeline ========
__global__ __launch_bounds__(256, 3) void k3(const float* __restrict__ gt,
                                             const float* __restrict__ et,
                                             const float* __restrict__ arel,
                                             const float* __restrict__ w,
                                             const float* __restrict__ tr,
                                             float* __restrict__ outp) {
  __shared__ __align__(16) float smem[10240];  // 2 x (A[16][128] + B[16][192]) = 40 KB
  const int tid = threadIdx.x;
  const int tx = tid & 15, ty = tid >> 4;
  const int wv = tid >> 6, ln = tid & 63;
  const int v0 = blockIdx.x * 64;
  const int r0 = blockIdx.x * 192;
  const int b0 = blockIdx.y * 128;
  float acc[8][12];
#pragma unroll
  for (int i = 0; i < 8; ++i)
#pragma unroll
    for (int n = 0; n < 12; ++n) acc[i][n] = 0.f;

#define STAGE(cur, ks) do {                                                          \
    float* Ab = smem + (cur) * 5120;                                                 \
    float* Bb = Ab + 2048;                                                           \
    int k0s = (ks) * 16;                                                             \
    _Pragma("unroll")                                                                \
    for (int p = 0; p < 2; ++p) {                                                    \
      int flat = p * 1024 + wv * 256 + ln * 4;                                       \
      int kk = flat >> 7, bb = flat & 127;                                           \
      __builtin_amdgcn_global_load_lds(                                              \
        (const __attribute__((address_space(1))) float*)(et + (size_t)(k0s + kk) * 1024 + b0 + bb), \
        (__attribute__((address_space(3))) float*)(Ab + p * 1024 + wv * 256), 16, 0, 0); \
    }                                                                                \
    _Pragma("unroll")                                                                \
    for (int p = 0; p < 3; ++p) {                                                    \
      int flat = p * 1024 + wv * 256 + ln * 4;                                       \
      int kk = flat / 192, rr = flat - kk * 192;                                     \
      __builtin_amdgcn_global_load_lds(                                              \
        (const __attribute__((address_space(1))) float*)(gt + (size_t)(k0s + kk) * RS + r0 + rr), \
        (__attribute__((address_space(3))) float*)(Bb + p * 1024 + wv * 256), 16, 0, 0); \
    }                                                                                \
  } while (0)

  STAGE(0, 0);
  __syncthreads();
  for (int ks = 0; ks < 12; ++ks) {
    int cur = ks & 1;
    if (ks < 11) STAGE(cur ^ 1, ks + 1);
    const float* Al = smem + cur * 5120;
    const float* Bl = Al + 2048;
#pragma unroll 4
    for (int kk = 0; kk < 16; ++kk) {
      float a[8], bf[12];
      *(float4*)&a[0]  = *(const float4*)(Al + kk * 128 + ty * 8);
      *(float4*)&a[4]  = *(const float4*)(Al + kk * 128 + ty * 8 + 4);
      *(float4*)&bf[0] = *(const float4*)(Bl + kk * 192 + tx * 12);
      *(float4*)&bf[4] = *(const float4*)(Bl + kk * 192 + tx * 12 + 4);
      *(float4*)&bf[8] = *(const float4*)(Bl + kk * 192 + tx * 12 + 8);
#pragma unroll
      for (int i = 0; i < 8; ++i)
#pragma unroll
        for (int n = 0; n < 12; ++n)
          acc[i][n] = fmaf(a[i], bf[n], acc[i][n]);
    }
    __syncthreads();   // drains vmcnt (next-tile DMA) + syncs buffer reuse
  }
#undef STAGE

  // ---- epilogue staging (reuse smem; all waves past final barrier) ----
  float* Ard = smem;             // [128][64]
  float* wl  = smem + 8192;      // [64][5]
  float* tl  = smem + 8192 + 320;  // [128][3]
  for (int idx = tid; idx < 128 * 60; idx += 256) {
    int bb = idx / 60, r = idx % 60;
    Ard[bb * 64 + r] = arel[(size_t)(b0 + bb) * 60 + r];
  }
  for (int idx = tid; idx < 320; idx += 256) {
    int vv = idx / 5, j = idx % 5;
    int v = v0 + vv; if (v > NV - 1) v = NV - 1;
    wl[idx] = w[v * 5 + j];
  }
  for (int idx = tid; idx < 384; idx += 256) tl[idx] = tr[b0 * 3 + idx];
  __syncthreads();

#define STORE_V(T, vi_) do {                                                   \
    int v = v0 + tx * 4 + (vi_);                                               \
    if (v < NV) {                                                              \
      float x = acc[i][(vi_) * 3 + 0], y = acc[i][(vi_) * 3 + 1], z = acc[i][(vi_) * 3 + 2]; \
      float ox = fmaf(T[0], x, fmaf(T[1], y, fmaf(T[2], z, T[3] + t0)));       \
      float oy = fmaf(T[4], x, fmaf(T[5], y, fmaf(T[6], z, T[7] + t1)));       \
      float oz = fmaf(T[8], x, fmaf(T[9], y, fmaf(T[10], z, T[11] + t2)));     \
      float* op = outp + (size_t)(b0 + b) * OSTR + (size_t)v * 3;              \
      op[0] = ox; op[1] = oy; op[2] = oz;                                      \
    } } while (0)

#pragma unroll
  for (int i = 0; i < 8; ++i) {
    int b = ty * 8 + i;
    float t0 = tl[b * 3 + 0], t1 = tl[b * 3 + 1], t2 = tl[b * 3 + 2];
#pragma unroll
    for (int h = 0; h < 2; ++h) {
      float T0[12], T1[12];
#pragma unroll
      for (int r = 0; r < 12; ++r) { T0[r] = 0.f; T1[r] = 0.f; }
      int vv0 = tx * 4 + 2 * h;
#pragma unroll
      for (int j = 0; j < 5; ++j) {
        float Aj[12];
        *(float4*)&Aj[0] = *(const float4*)(Ard + b * 64 + j * 12 + 0);
        *(float4*)&Aj[4] = *(const float4*)(Ard + b * 64 + j * 12 + 4);
        *(float4*)&Aj[8] = *(const float4*)(Ard + b * 64 + j * 12 + 8);
        float w0 = wl[vv0 * 5 + j], w1 = wl[(vv0 + 1) * 5 + j];
#pragma unroll
        for (int r = 0; r < 12; ++r) {
          T0[r] = fmaf(w0, Aj[r], T0[r]);
          T1[r] = fmaf(w1, Aj[r], T1[r]);
        }
      }
      STORE_V(T0, 2 * h);
      STORE_V(T1, 2 * h + 1);
    }
  }
#undef STORE_V
}

// ============ K4: landmarks ============
__global__ void k4(const int* __restrict__ faces, const int* __restrict__ lfi,
                   const float* __restrict__ bary, float* __restrict__ outp) {
  int idx = blockIdx.x * 256 + threadIdx.x;
  if (idx >= BN * NL * 3) return;
  int b = idx / (NL * 3), rem = idx % (NL * 3);
  int l = rem / 3, i = rem % 3;
  int fi = lfi[l];
  float s = 0.f;
#pragma unroll
  for (int f = 0; f < 3; ++f) {
    int vid = faces[fi * 3 + f];
    s += bary[l * 3 + f] * outp[(size_t)b * OSTR + (size_t)vid * 3 + i];
  }
  outp[(size_t)b * OSTR + (size_t)(NV + l) * 3 + i] = s;
}

extern "C" void kernel_launch(void* const* d_in, const int* in_sizes, int n_in,
                              void* d_out, int out_size, void* d_ws, size_t ws_size,
                              hipStream_t stream) {
  const float* shp  = (const float*)d_in[0];
  const float* expr = (const float*)d_in[1];
  const float* pose = (const float*)d_in[2];
  const float* eye  = (const float*)d_in[3];
  const float* tr   = (const float*)d_in[4];
  const float* vt   = (const float*)d_in[5];
  const float* sd   = (const float*)d_in[6];
  const float* pd   = (const float*)d_in[7];
  const float* jreg = (const float*)d_in[8];
  const float* w    = (const float*)d_in[9];
  const int* faces  = (const int*)d_in[10];
  const int* lfi    = (const int*)d_in[11];
  const float* bary = (const float*)d_in[12];
  float* ws = (float*)d_ws;
  float* jsx  = ws + O_JSX;
  float* part = ws + O_PART;
  float* et   = ws + O_ET;
  float* arel = ws + O_AREL;
  float* gt   = ws + O_GT;
  float* outp = (float*)d_out;

  k0a<<<dim3(476, 5), 256, 0, stream>>>(sd, gt);
  k0b<<<(42 * RS + 255) / 256, 256, 0, stream>>>(pd, vt, gt);
  k1a<<<79, 256, 0, stream>>>(sd, vt, jreg, part);
  k1b<<<1, 512, 0, stream>>>(part, jsx);
  k2<<<1024, 64, 0, stream>>>(shp, expr, pose, eye, jsx, et, arel);
  k3<<<dim3(79, 8), 256, 0, stream>>>(gt, et, arel, w, tr, outp);
  k4<<<816, 256, 0, stream>>>(faces, lfi, bary, outp);
}

// Round 3
// 93.243 us; speedup vs baseline: 2.6105x; 2.0700x over previous
//
#include <hip/hip_runtime.h>
#include <math.h>

#define BN 1024
#define NV 5023
#define NL 68
#define NVP 5088       // padded verts (mult of 16)
#define NPL 15264      // 3*NVP rows per k of packed G
#define OSTR 15273     // (V+L)*3
#define KTOT 192
#define NG 24          // 192/8 k-groups

typedef unsigned short u16;
typedef short bf16x8 __attribute__((ext_vector_type(8)));
typedef u16 u16x8 __attribute__((ext_vector_type(8)));
typedef float f32x4 __attribute__((ext_vector_type(4)));

// ---------------- workspace layout (floats) ----------------
#define O_JSX  0          // jsx[15][152]
#define O_PART 4096       // part[80][15][160]
#define O_AREL 200704     // arel[1024][60]
#define O_EH   262144     // E_ph bf16 [24][1024][8]   (98304 floats)
#define O_EL   360448
#define O_GH   458752     // G_ph bf16 [24][15264][8]  (1465344 floats)
#define O_GL   1924096

__device__ __forceinline__ u16 f2bf(float x) {
  unsigned u = __float_as_uint(x);
  return (u16)((u + 0x7FFFu + ((u >> 16) & 1u)) >> 16);
}
__device__ __forceinline__ float bf2f(u16 h) {
  return __uint_as_float(((unsigned)h) << 16);
}

// ============ K0: pack basis G -> bf16 hi/lo (k-major, [g][c*NVP+v][8]) + J partials ====
__global__ __launch_bounds__(256) void k0(const float* __restrict__ sd,
                                          const float* __restrict__ pd,
                                          const float* __restrict__ vt,
                                          const float* __restrict__ jreg,
                                          float* __restrict__ part,
                                          u16* __restrict__ gph,
                                          u16* __restrict__ gpl) {
  __shared__ float ldsT[64 * 208];
  __shared__ float jr[320];
  const int tid = threadIdx.x;
  const int v0 = blockIdx.x * 64;
  const int c = blockIdx.y;
  // phase 1: stage [64 v][192 k] for this c-plane
  for (int idx = tid; idx < 64 * 150; idx += 256) {
    int vv = idx / 150, k = idx - vv * 150;
    int v = v0 + vv;
    ldsT[vv * 208 + k] = (v < NV) ? sd[((size_t)v * 3 + c) * 150 + k] : 0.f;
  }
  for (int idx = tid; idx < 36 * 64; idx += 256) {
    int kk = idx >> 6, vv = idx & 63;
    int v = v0 + vv;
    ldsT[vv * 208 + 150 + kk] = (v < NV) ? pd[(size_t)kk * 15069 + (size_t)v * 3 + c] : 0.f;
  }
  for (int idx = tid; idx < 64 * 6; idx += 256) {
    int vv = idx / 6, kk = idx - vv * 6;  // k = 186..191
    int v = v0 + vv;
    ldsT[vv * 208 + 186 + kk] = (kk == 0 && v < NV) ? vt[(size_t)v * 3 + c] : 0.f;
  }
  for (int idx = tid; idx < 320; idx += 256) {
    int j = idx >> 6, vv = idx & 63;
    int v = v0 + vv;
    jr[idx] = (v < NV) ? jreg[(size_t)j * NV + v] : 0.f;
  }
  __syncthreads();
  // phase 2a: J partials over [sd|vt] columns
  if (tid < 192) {
    int k = tid;
    float s0 = 0.f, s1 = 0.f, s2 = 0.f, s3 = 0.f, s4 = 0.f;
    for (int vv = 0; vv < 64; ++vv) {
      float x = ldsT[vv * 208 + k];
      s0 = fmaf(jr[vv], x, s0);
      s1 = fmaf(jr[64 + vv], x, s1);
      s2 = fmaf(jr[128 + vv], x, s2);
      s3 = fmaf(jr[192 + vv], x, s3);
      s4 = fmaf(jr[256 + vv], x, s4);
    }
    int km = (k < 150) ? k : ((k == 186) ? 150 : -1);
    if (km >= 0) {
      size_t base = ((size_t)blockIdx.x * 15 + c) * 160;
      part[base + 0 * 480 + km] = s0;   // (vch*15 + j*3 + c)*160
      part[base + 1 * 480 + km] = s1;
      part[base + 2 * 480 + km] = s2;
      part[base + 3 * 480 + km] = s3;
      part[base + 4 * 480 + km] = s4;
    }
  }
  // phase 2b: pack to bf16 hi/lo
  {
    int q = tid >> 6, vv = tid & 63;
    int v = v0 + vv;
    if (v < NVP) {
#pragma unroll
      for (int gg = 0; gg < 6; ++gg) {
        int g = q * 6 + gg;
        u16x8 h8, l8;
#pragma unroll
        for (int j = 0; j < 8; ++j) {
          float x = ldsT[vv * 208 + g * 8 + j];
          u16 h = f2bf(x);
          h8[j] = h;
          l8[j] = f2bf(x - bf2f(h));
        }
        size_t off = ((size_t)g * NPL + (size_t)c * NVP + v) * 8;
        *(u16x8*)(gph + off) = h8;
        *(u16x8*)(gpl + off) = l8;
      }
    }
  }
}

// ============ K1b: reduce J partials -> jsx[15][152] ============
__global__ void k1b(const float* __restrict__ part, float* __restrict__ jsx) {
  int jc = blockIdx.x, k = threadIdx.x;
  if (k < 151) {
    float s = 0.f;
    for (int vch = 0; vch < 80; ++vch)
      s += part[((size_t)vch * 15 + jc) * 160 + k];
    jsx[jc * 152 + k] = s;
  }
}

// ============ K2: per-batch J, Rodrigues, chain, A_rel, packed E hi/lo ============
__global__ __launch_bounds__(64) void k2(const float* __restrict__ shp,
                                         const float* __restrict__ expr,
                                         const float* __restrict__ pose,
                                         const float* __restrict__ eye,
                                         const float* __restrict__ jsx,
                                         u16* __restrict__ eph,
                                         u16* __restrict__ epl,
                                         float* __restrict__ arel) {
  int b = blockIdx.x, t = threadIdx.x;
  __shared__ float bet[150];
  __shared__ float Rm[5][9];
  __shared__ float Tl[5][16];
  __shared__ float Am[5][16];
  __shared__ float Jl[15];
  for (int i = t; i < 150; i += 64)
    bet[i] = (i < 100) ? shp[b * 100 + i] : expr[b * 50 + (i - 100)];
  __syncthreads();
  if (t < 60) {
    int jc = t >> 2, sub = t & 3;
    float acc = 0.f;
    for (int m = 0; m < 38; ++m) {
      int l = sub + 4 * m;
      if (l < 150) acc += jsx[jc * 152 + l] * bet[l];
      else if (l == 150) acc += jsx[jc * 152 + 150];
    }
    acc += __shfl_xor(acc, 1);
    acc += __shfl_xor(acc, 2);
    if (sub == 0) Jl[jc] = acc;
  }
  __syncthreads();
  if (t < 5) {
    float r0, r1, r2;
    if (t == 0)      { r0 = pose[b*6+0]; r1 = pose[b*6+1]; r2 = pose[b*6+2]; }
    else if (t == 2) { r0 = pose[b*6+3]; r1 = pose[b*6+4]; r2 = pose[b*6+5]; }
    else if (t == 3) { r0 = eye[b*6+0];  r1 = eye[b*6+1];  r2 = eye[b*6+2];  }
    else if (t == 4) { r0 = eye[b*6+3];  r1 = eye[b*6+4];  r2 = eye[b*6+5];  }
    else             { r0 = 0.f; r1 = 0.f; r2 = 0.f; }
    float ang = sqrtf(r0*r0 + r1*r1 + r2*r2 + 1e-16f);
    float ax = r0/ang, ay = r1/ang, az = r2/ang;
    float s = sinf(ang), cc = cosf(ang), o = 1.f - cc;
    float R0 = 1.f - o*(ay*ay+az*az);
    float R1 = -s*az + o*ax*ay;
    float R2 =  s*ay + o*ax*az;
    float R3 =  s*az + o*ax*ay;
    float R4 = 1.f - o*(ax*ax+az*az);
    float R5 = -s*ax + o*ay*az;
    float R6 = -s*ay + o*ax*az;
    float R7 =  s*ax + o*ay*az;
    float R8 = 1.f - o*(ax*ax+ay*ay);
    Rm[t][0]=R0; Rm[t][1]=R1; Rm[t][2]=R2; Rm[t][3]=R3; Rm[t][4]=R4;
    Rm[t][5]=R5; Rm[t][6]=R6; Rm[t][7]=R7; Rm[t][8]=R8;
    int par = (t == 0) ? -1 : ((t == 1) ? 0 : 1);
    float j0 = Jl[t*3+0], j1 = Jl[t*3+1], j2 = Jl[t*3+2];
    if (par >= 0) { j0 -= Jl[par*3+0]; j1 -= Jl[par*3+1]; j2 -= Jl[par*3+2]; }
    Tl[t][0]=R0; Tl[t][1]=R1; Tl[t][2]=R2;  Tl[t][3]=j0;
    Tl[t][4]=R3; Tl[t][5]=R4; Tl[t][6]=R5;  Tl[t][7]=j1;
    Tl[t][8]=R6; Tl[t][9]=R7; Tl[t][10]=R8; Tl[t][11]=j2;
    Tl[t][12]=0.f; Tl[t][13]=0.f; Tl[t][14]=0.f; Tl[t][15]=1.f;
  }
  __syncthreads();
  if (t < 16) Am[0][t] = Tl[0][t];
  __syncthreads();
  if (t < 16) {
    int m = t / 4, n = t % 4;
    float s = 0.f;
#pragma unroll
    for (int k = 0; k < 4; ++k) s += Am[0][m*4+k] * Tl[1][k*4+n];
    Am[1][t] = s;
  }
  __syncthreads();
  if (t < 48) {
    int jj = 2 + t / 16, tt = t % 16;
    int m = tt / 4, n = tt % 4;
    float s = 0.f;
#pragma unroll
    for (int k = 0; k < 4; ++k) s += Am[1][m*4+k] * Tl[jj][k*4+n];
    Am[jj][tt] = s;
  }
  __syncthreads();
  if (t < 60) {
    int j = t / 12, rr = (t % 12) / 4, cc = t % 4;
    float val = Am[j][rr*4+cc];
    if (cc == 3)
      val = Am[j][rr*4+3] - (Am[j][rr*4+0]*Jl[j*3+0] + Am[j][rr*4+1]*Jl[j*3+1] + Am[j][rr*4+2]*Jl[j*3+2]);
    arel[b * 60 + t] = val;
  }
  for (int k = t; k < 192; k += 64) {
    float val;
    if (k < 150) val = bet[k];
    else if (k < 186) {
      int kk = k - 150;
      int j = kk / 9 + 1, rc = kk % 9;
      val = Rm[j][rc] - ((rc == 0 || rc == 4 || rc == 8) ? 1.f : 0.f);
    } else if (k == 186) val = 1.f;
    else val = 0.f;
    u16 h = f2bf(val);
    u16 lo = f2bf(val - bf2f(h));
    int g = k >> 3, j8 = k & 7;
    eph[((size_t)g * 1024 + b) * 8 + j8] = h;
    epl[((size_t)g * 1024 + b) * 8 + j8] = lo;
  }
}

// ============ K3: split-bf16 MFMA GEMM + lane-local LBS blend ============
__global__ __launch_bounds__(512, 2) void k3(const u16* __restrict__ eph,
                                             const u16* __restrict__ epl,
                                             const u16* __restrict__ gph,
                                             const u16* __restrict__ gpl,
                                             const float* __restrict__ arel,
                                             const float* __restrict__ w,
                                             const float* __restrict__ tr,
                                             float* __restrict__ outp) {
  __shared__ __align__(16) float sAr[128 * 68];
  __shared__ float sTr[128 * 4];
  const int tid = threadIdx.x;
  const int lane = tid & 63, wave = tid >> 6;
  const int wr = wave >> 2, wc = wave & 3;
  const int l15 = lane & 15, g0 = lane >> 4;
  const int b_blk = blockIdx.y * 128;
  const int vglob = blockIdx.x * 64 + wc * 16 + l15;

  f32x4 acc[4][3];
#pragma unroll
  for (int mt = 0; mt < 4; ++mt)
#pragma unroll
    for (int c = 0; c < 3; ++c) { acc[mt][c][0]=0.f; acc[mt][c][1]=0.f; acc[mt][c][2]=0.f; acc[mt][c][3]=0.f; }

  size_t aoff = ((size_t)g0 * 1024 + (size_t)(b_blk + wr * 64 + l15)) * 8;
  size_t boff = ((size_t)g0 * NPL + (size_t)vglob) * 8;

#pragma unroll 2
  for (int ks = 0; ks < 6; ++ks) {
    bf16x8 ah[4], al[4], bh[3], bl[3];
#pragma unroll
    for (int mt = 0; mt < 4; ++mt) {
      ah[mt] = *(const bf16x8*)(eph + aoff + mt * 128);
      al[mt] = *(const bf16x8*)(epl + aoff + mt * 128);
    }
#pragma unroll
    for (int c = 0; c < 3; ++c) {
      bh[c] = *(const bf16x8*)(gph + boff + (size_t)c * (NVP * 8));
      bl[c] = *(const bf16x8*)(gpl + boff + (size_t)c * (NVP * 8));
    }
#pragma unroll
    for (int c = 0; c < 3; ++c)
#pragma unroll
      for (int mt = 0; mt < 4; ++mt) {
        acc[mt][c] = __builtin_amdgcn_mfma_f32_16x16x32_bf16(ah[mt], bh[c], acc[mt][c], 0, 0, 0);
        acc[mt][c] = __builtin_amdgcn_mfma_f32_16x16x32_bf16(ah[mt], bl[c], acc[mt][c], 0, 0, 0);
        acc[mt][c] = __builtin_amdgcn_mfma_f32_16x16x32_bf16(al[mt], bh[c], acc[mt][c], 0, 0, 0);
      }
    aoff += (size_t)4 * 1024 * 8;
    boff += (size_t)4 * NPL * 8;
  }

  // ---- epilogue: stage arel + translation, lane-local blend ----
  for (int idx = tid; idx < 128 * 60; idx += 512) {
    int bb = idx / 60, r = idx - bb * 60;
    sAr[bb * 68 + r] = arel[(size_t)(b_blk + bb) * 60 + r];
  }
  for (int idx = tid; idx < 384; idx += 512) {
    int bb = idx / 3;
    sTr[bb * 4 + (idx - bb * 3)] = tr[(size_t)b_blk * 3 + idx];
  }
  __syncthreads();

  int v_c = vglob < NV ? vglob : NV - 1;
  float wreg[5];
#pragma unroll
  for (int j = 0; j < 5; ++j) wreg[j] = w[(size_t)v_c * 5 + j];

#pragma unroll
  for (int mt = 0; mt < 4; ++mt) {
#pragma unroll
    for (int r = 0; r < 4; ++r) {
      int bl_ = wr * 64 + mt * 16 + g0 * 4 + r;
      const float4* Ar = (const float4*)(sAr + bl_ * 68);
      float4 T0 = {0.f,0.f,0.f,0.f}, T1 = {0.f,0.f,0.f,0.f}, T2 = {0.f,0.f,0.f,0.f};
#pragma unroll
      for (int j = 0; j < 5; ++j) {
        float wj = wreg[j];
        float4 x = Ar[j * 3 + 0], y = Ar[j * 3 + 1], z = Ar[j * 3 + 2];
        T0.x = fmaf(wj, x.x, T0.x); T0.y = fmaf(wj, x.y, T0.y);
        T0.z = fmaf(wj, x.z, T0.z); T0.w = fmaf(wj, x.w, T0.w);
        T1.x = fmaf(wj, y.x, T1.x); T1.y = fmaf(wj, y.y, T1.y);
        T1.z = fmaf(wj, y.z, T1.z); T1.w = fmaf(wj, y.w, T1.w);
        T2.x = fmaf(wj, z.x, T2.x); T2.y = fmaf(wj, z.y, T2.y);
        T2.z = fmaf(wj, z.z, T2.z); T2.w = fmaf(wj, z.w, T2.w);
      }
      float px = acc[mt][0][r], py = acc[mt][1][r], pz = acc[mt][2][r];
      float ox = fmaf(T0.x, px, fmaf(T0.y, py, fmaf(T0.z, pz, T0.w + sTr[bl_ * 4 + 0])));
      float oy = fmaf(T1.x, px, fmaf(T1.y, py, fmaf(T1.z, pz, T1.w + sTr[bl_ * 4 + 1])));
      float oz = fmaf(T2.x, px, fmaf(T2.y, py, fmaf(T2.z, pz, T2.w + sTr[bl_ * 4 + 2])));
      if (vglob < NV) {
        float* op = outp + (size_t)(b_blk + bl_) * OSTR + (size_t)vglob * 3;
        op[0] = ox; op[1] = oy; op[2] = oz;
      }
    }
  }
}

// ============ K4: landmarks ============
__global__ void k4(const int* __restrict__ faces, const int* __restrict__ lfi,
                   const float* __restrict__ bary, float* __restrict__ outp) {
  int idx = blockIdx.x * 256 + threadIdx.x;
  if (idx >= BN * NL * 3) return;
  int b = idx / (NL * 3), rem = idx % (NL * 3);
  int l = rem / 3, i = rem % 3;
  int fi = lfi[l];
  float s = 0.f;
#pragma unroll
  for (int f = 0; f < 3; ++f) {
    int vid = faces[fi * 3 + f];
    s += bary[l * 3 + f] * outp[(size_t)b * OSTR + (size_t)vid * 3 + i];
  }
  outp[(size_t)b * OSTR + (size_t)(NV + l) * 3 + i] = s;
}

extern "C" void kernel_launch(void* const* d_in, const int* in_sizes, int n_in,
                              void* d_out, int out_size, void* d_ws, size_t ws_size,
                              hipStream_t stream) {
  const float* shp  = (const float*)d_in[0];
  const float* expr = (const float*)d_in[1];
  const float* pose = (const float*)d_in[2];
  const float* eye  = (const float*)d_in[3];
  const float* tr   = (const float*)d_in[4];
  const float* vt   = (const float*)d_in[5];
  const float* sd   = (const float*)d_in[6];
  const float* pd   = (const float*)d_in[7];
  const float* jreg = (const float*)d_in[8];
  const float* w    = (const float*)d_in[9];
  const int* faces  = (const int*)d_in[10];
  const int* lfi    = (const int*)d_in[11];
  const float* bary = (const float*)d_in[12];
  float* ws = (float*)d_ws;
  float* jsx  = ws + O_JSX;
  float* part = ws + O_PART;
  float* arel = ws + O_AREL;
  u16* eph = (u16*)(ws + O_EH);
  u16* epl = (u16*)(ws + O_EL);
  u16* gph = (u16*)(ws + O_GH);
  u16* gpl = (u16*)(ws + O_GL);
  float* outp = (float*)d_out;

  k0<<<dim3(80, 3), 256, 0, stream>>>(sd, pd, vt, jreg, part, gph, gpl);
  k1b<<<15, 160, 0, stream>>>(part, jsx);
  k2<<<1024, 64, 0, stream>>>(shp, expr, pose, eye, jsx, eph, epl, arel);
  k3<<<dim3(79, 8), 512, 0, stream>>>(eph, epl, gph, gpl, arel, w, tr, outp);
  k4<<<816, 256, 0, stream>>>(faces, lfi, bary, outp);
}